// Round 8
// baseline (147.603 us; speedup 1.0000x reference)
//
#include <hip/hip_runtime.h>

// ReflectionRayTracer: 8192 rays x 2048 quad surfaces. out[ray][surf] = t*mask.
//
// R8: maximal write-locality test (the last untested variable).
// Effective write BW has been pinned at ~2.9 TB/s across width(1/2)/NT/occupancy/
// fusion A-Bs; theory: every prior config had blocks writing 1-4 KB chunks with
// 8-KB jumps -> ~1-2k interleaved strided streams at the HBM controllers ->
// partial-page writes at ~half streaming BW.
// This round: one block covers a FULL output row (512 thr x SPT=4 = 2048 cols),
// RPB=8 rows -> each block writes one contiguous 64-KB region, one full 8-KB
// row per iteration, 1-KB dwordx4 bursts per wave. 1024 blocks.
//  - split precompute (coeffs in d_ws) so the SPT=4 preamble doesn't tax the loop.
//  - __launch_bounds__(512,6): ~84 VGPR cap (52 coeff + ~25 working) -> 24 waves/CU.
// Per-pair math unchanged from R6/R7 (rcp coeffs + fma dots + min3) -> absmax
// expected ~2.6-4.1, threshold 7.24.
// If neutral: all controllable variables exhausted -> declare roofline at ~22 us.

#define N_RAYS 8192
#define N_SURF 2048
constexpr int TPB = 512;  // threads per block
constexpr int SPT = 4;    // surfaces per thread -> block covers 2048 cols = full row
constexpr int RPB = 8;    // rays per block -> 1024 blocks, 64 KB contiguous per block

__device__ __forceinline__ float safef(float x) {
    return (x == 0.0f) ? 1e-18f : x;   // jnp.where(x==0, EPS, x)
}

struct Coeffs {
    float vx, vy, vz, k;          // plane
    float g0, g1, g2;             // gam   = g  . r
    float bb0, bb1, bb2;          // beta  = bb . r
    float aa0, aa1, aa2;          // alpha = aa . r
};

__global__ __launch_bounds__(256) void precompute_kernel(
    const float* __restrict__ V, float* __restrict__ C)
{
    const int s = blockIdx.x * 256 + threadIdx.x;

    const float4 p0 = *(const float4*)(V + (size_t)s * 12);
    const float4 p1 = *(const float4*)(V + (size_t)s * 12 + 4);
    const float4 p2 = *(const float4*)(V + (size_t)s * 12 + 8);
    const float ax = p0.x, ay = p0.y, az = p0.z;       // a = V[s][0]
    const float bx = p0.w, by = p1.x, bz = p1.y;       // b = V[s][1]
    const float cx = p1.z, cy = p1.w, cz = p2.x;       // c = V[s][2]
    const float wx = p2.y, wy = p2.z, wz = p2.w;       // V[s][3]

    // Plane: v = normalize(cross(b-a, c-a)); k = -dot(v, V[s][3])
    const float e0x = bx - ax, e0y = by - ay, e0z = bz - az;
    const float e1x = cx - ax, e1y = cy - ay, e1z = cz - az;
    const float nx = e0y * e1z - e0z * e1y;
    const float ny = e0z * e1x - e0x * e1z;
    const float nz = e0x * e1y - e0y * e1x;
    const float rn = __builtin_amdgcn_rsqf(fmaf(nx, nx, fmaf(ny, ny, nz * nz)));
    const float vx = nx * rn, vy = ny * rn, vz = nz * rn;
    const float k = -fmaf(vx, wx, fmaf(vy, wy, vz * wz));

    // Reference constants:
    const float B  = ax * bz - az * bx;
    const float D  = ax * by - ay * bx;                 // G == D
    const float E  = ax * cz - az * cx;
    const float P  = ay * cx - ax * cy;
    const float F  = B * P;
    const float rden = __builtin_amdgcn_rcpf(safef(D * fmaf(E, D, F)));
    const float rD   = __builtin_amdgcn_rcpf(safef(D));
    const float rAX  = __builtin_amdgcn_rcpf(safef(ax));

    const float DB = D * B, DD = D * D;
    const float g0 = (DB * ay - DD * az) * rden;
    const float g1 = -(DB * ax) * rden;
    const float g2 = (DD * ax) * rden;
    const float bp = P * rD;
    const float bb0 = fmaf(bp, g0, -ay * rD);
    const float bb1 = fmaf(bp, g1,  ax * rD);
    const float bb2 = bp * g2;
    const float ab = -bx * rAX, ac = -cx * rAX;
    const float aa0 = fmaf(ab, bb0, fmaf(ac, g0, rAX));
    const float aa1 = fmaf(ab, bb1, ac * g1);
    const float aa2 = fmaf(ab, bb2, ac * g2);

    float4* c4 = (float4*)(C + (size_t)s * 16);
    c4[0] = make_float4(vx, vy, vz, k);
    c4[1] = make_float4(g0, g1, g2, 0.0f);
    c4[2] = make_float4(bb0, bb1, bb2, 0.0f);
    c4[3] = make_float4(aa0, aa1, aa2, 0.0f);
}

__device__ __forceinline__ float trace_pair(
    const Coeffs& c, float o0, float o1, float o2, float d0, float d1, float d2)
{
    const float vo_k = fmaf(o0, c.vx, fmaf(o1, c.vy, fmaf(o2, c.vz, c.k)));  // k + v.o
    const float vd   = fmaf(d0, c.vx, fmaf(d1, c.vy, d2 * c.vz));
    const float t    = -vo_k * __builtin_amdgcn_rcpf(vd);

    const float rx = fmaf(t, d0, o0);
    const float ry = fmaf(t, d1, o1);
    const float rz = fmaf(t, d2, o2);

    const float gam   = fmaf(c.g0,  rx, fmaf(c.g1,  ry, c.g2  * rz));
    const float beta  = fmaf(c.bb0, rx, fmaf(c.bb1, ry, c.bb2 * rz));
    const float alpha = fmaf(c.aa0, rx, fmaf(c.aa1, ry, c.aa2 * rz));

    const float mn = fminf(fminf(beta, gam), alpha);   // v_min3_f32
    return (mn > 0.0f) ? t : 0.0f;
}

__global__ __launch_bounds__(TPB, 6) void trace_kernel(
    const float* __restrict__ o, const float* __restrict__ dr,
    const float* __restrict__ C, float* __restrict__ out)
{
    const int s0 = threadIdx.x * SPT;       // block spans the full 2048-col row

    Coeffs c[SPT];
#pragma unroll
    for (int j = 0; j < SPT; ++j) {
        const float4* c4 = (const float4*)(C + (size_t)(s0 + j) * 16);
        const float4 q0 = c4[0], q1 = c4[1], q2 = c4[2], q3 = c4[3];
        c[j].vx = q0.x; c[j].vy = q0.y; c[j].vz = q0.z; c[j].k = q0.w;
        c[j].g0 = q1.x; c[j].g1 = q1.y; c[j].g2 = q1.z;
        c[j].bb0 = q2.x; c[j].bb1 = q2.y; c[j].bb2 = q2.z;
        c[j].aa0 = q3.x; c[j].aa1 = q3.y; c[j].aa2 = q3.z;
    }

    const int ray0 = blockIdx.x * RPB;
    float* outp = out + (size_t)ray0 * N_SURF + s0;
#pragma unroll 2
    for (int i = 0; i < RPB; ++i) {
        const int ray = ray0 + i;
        // Block-uniform ray loads -> scalar loads.
        const float o0 = o[ray * 3 + 0], o1 = o[ray * 3 + 1], o2 = o[ray * 3 + 2];
        const float d0 = dr[ray * 3 + 0], d1 = dr[ray * 3 + 1], d2 = dr[ray * 3 + 2];

        float res[SPT];
#pragma unroll
        for (int j = 0; j < SPT; ++j)
            res[j] = trace_pair(c[j], o0, o1, o2, d0, d1, d2);

        // Wave writes 1 KB contiguous; block writes the full 8-KB row this iter.
        *(float4*)(outp + (size_t)i * N_SURF) = *(const float4*)res;  // 16B-aligned
    }
}

extern "C" void kernel_launch(void* const* d_in, const int* in_sizes, int n_in,
                              void* d_out, int out_size, void* d_ws, size_t ws_size,
                              hipStream_t stream) {
    const float* o  = (const float*)d_in[0];
    const float* dr = (const float*)d_in[1];
    const float* V  = (const float*)d_in[2];
    float* out = (float*)d_out;
    float* C = (float*)d_ws;   // 2048 * 16 * 4 B = 128 KiB

    precompute_kernel<<<dim3(N_SURF / 256), dim3(256), 0, stream>>>(V, C);
    trace_kernel<<<dim3(N_RAYS / RPB), dim3(TPB), 0, stream>>>(o, dr, C, out);
}

// Round 9
// 85.982 us; speedup vs baseline: 1.7167x; 1.7167x over previous
//
#include <hip/hip_runtime.h>

// ReflectionRayTracer: 8192 rays x 2048 quad surfaces. out[ray][surf] = t*mask.
//
// R9: the write-locality test R8 was supposed to be, spill-free.
// R8 post-mortem: __launch_bounds__(512,6) + 52-float coeff array -> compiler
// allocated 40 VGPR and spilled to scratch (FETCH 50 MB of spill reloads,
// WRITE 132 MB = 64 MiB output + 66 MB spill). Invalid test.
// Fix: SPT=2 (26 coeff floats — proven spill-free at 64 VGPR / 8 waves per SIMD
// in R7) and get full-row coverage from TPB=1024 instead:
//  - TPB=1024 x SPT=2 = 2048 cols = one FULL output row per block.
//  - RPB=16 -> grid = 512 blocks = exactly 2 blocks/CU = 32 waves/CU (full occ).
//  - Each block writes a contiguous 128-KB region (16 sequential 8-KB rows);
//    one block per row; 512 long sequential write streams vs R6's 2048 short
//    interleaved ones jumping 8 KB per iteration.
// Per-pair math unchanged (rcp coeffs + fma dots + min3) -> absmax ~2.6-4.1.
// Gate: VGPR_Count <= 64, FETCH < 3 MB, WRITE ~ 65536 KB. If spill-free but
// neutral, all controllable variables are exhausted -> roofline at ~22 us.

#define N_RAYS 8192
#define N_SURF 2048
constexpr int TPB = 1024; // threads per block
constexpr int SPT = 2;    // surfaces per thread -> block covers the full row
constexpr int RPB = 16;   // rays per block -> 512 blocks, 128 KB contiguous each

__device__ __forceinline__ float safef(float x) {
    return (x == 0.0f) ? 1e-18f : x;   // jnp.where(x==0, EPS, x)
}

struct Coeffs {
    float vx, vy, vz, k;          // plane
    float g0, g1, g2;             // gam   = g  . r
    float bb0, bb1, bb2;          // beta  = bb . r
    float aa0, aa1, aa2;          // alpha = aa . r
};

__device__ __forceinline__ Coeffs surface_coeffs(const float* __restrict__ V, int s)
{
    const float4 p0 = *(const float4*)(V + (size_t)s * 12);
    const float4 p1 = *(const float4*)(V + (size_t)s * 12 + 4);
    const float4 p2 = *(const float4*)(V + (size_t)s * 12 + 8);
    const float ax = p0.x, ay = p0.y, az = p0.z;       // a = V[s][0]
    const float bx = p0.w, by = p1.x, bz = p1.y;       // b = V[s][1]
    const float cx = p1.z, cy = p1.w, cz = p2.x;       // c = V[s][2]
    const float wx = p2.y, wy = p2.z, wz = p2.w;       // V[s][3]

    // Plane: v = normalize(cross(b-a, c-a)); k = -dot(v, V[s][3])
    const float e0x = bx - ax, e0y = by - ay, e0z = bz - az;
    const float e1x = cx - ax, e1y = cy - ay, e1z = cz - az;
    const float nx = e0y * e1z - e0z * e1y;
    const float ny = e0z * e1x - e0x * e1z;
    const float nz = e0x * e1y - e0y * e1x;
    const float rn = __builtin_amdgcn_rsqf(fmaf(nx, nx, fmaf(ny, ny, nz * nz)));
    const float vx = nx * rn, vy = ny * rn, vz = nz * rn;
    const float k = -fmaf(vx, wx, fmaf(vy, wy, vz * wz));

    // Reference constants:
    const float B  = ax * bz - az * bx;
    const float D  = ax * by - ay * bx;                 // G == D
    const float E  = ax * cz - az * cx;
    const float P  = ay * cx - ax * cy;
    const float F  = B * P;
    const float rden = __builtin_amdgcn_rcpf(safef(D * fmaf(E, D, F)));
    const float rD   = __builtin_amdgcn_rcpf(safef(D));
    const float rAX  = __builtin_amdgcn_rcpf(safef(ax));

    Coeffs c;
    c.vx = vx; c.vy = vy; c.vz = vz; c.k = k;
    const float DB = D * B, DD = D * D;
    c.g0 = (DB * ay - DD * az) * rden;
    c.g1 = -(DB * ax) * rden;
    c.g2 = (DD * ax) * rden;
    const float bp = P * rD;
    c.bb0 = fmaf(bp, c.g0, -ay * rD);
    c.bb1 = fmaf(bp, c.g1,  ax * rD);
    c.bb2 = bp * c.g2;
    const float ab = -bx * rAX, ac = -cx * rAX;
    c.aa0 = fmaf(ab, c.bb0, fmaf(ac, c.g0, rAX));
    c.aa1 = fmaf(ab, c.bb1, ac * c.g1);
    c.aa2 = fmaf(ab, c.bb2, ac * c.g2);
    return c;
}

__device__ __forceinline__ float trace_pair(
    const Coeffs& c, float o0, float o1, float o2, float d0, float d1, float d2)
{
    const float vo_k = fmaf(o0, c.vx, fmaf(o1, c.vy, fmaf(o2, c.vz, c.k)));  // k + v.o
    const float vd   = fmaf(d0, c.vx, fmaf(d1, c.vy, d2 * c.vz));
    const float t    = -vo_k * __builtin_amdgcn_rcpf(vd);

    const float rx = fmaf(t, d0, o0);
    const float ry = fmaf(t, d1, o1);
    const float rz = fmaf(t, d2, o2);

    const float gam   = fmaf(c.g0,  rx, fmaf(c.g1,  ry, c.g2  * rz));
    const float beta  = fmaf(c.bb0, rx, fmaf(c.bb1, ry, c.bb2 * rz));
    const float alpha = fmaf(c.aa0, rx, fmaf(c.aa1, ry, c.aa2 * rz));

    const float mn = fminf(fminf(beta, gam), alpha);   // v_min3_f32
    return (mn > 0.0f) ? t : 0.0f;
}

__global__ __launch_bounds__(TPB, 8) void trace_kernel(
    const float* __restrict__ o, const float* __restrict__ dr,
    const float* __restrict__ V, float* __restrict__ out)
{
    const int s0 = threadIdx.x * SPT;       // block spans the full 2048-col row

    const Coeffs ca = surface_coeffs(V, s0);
    const Coeffs cb = surface_coeffs(V, s0 + 1);

    const int ray0 = blockIdx.x * RPB;
    float* outp = out + (size_t)ray0 * N_SURF + s0;
#pragma unroll 4
    for (int i = 0; i < RPB; ++i) {
        const int ray = ray0 + i;
        // Block-uniform ray loads -> scalar loads.
        const float o0 = o[ray * 3 + 0], o1 = o[ray * 3 + 1], o2 = o[ray * 3 + 2];
        const float d0 = dr[ray * 3 + 0], d1 = dr[ray * 3 + 1], d2 = dr[ray * 3 + 2];

        float2 res;
        res.x = trace_pair(ca, o0, o1, o2, d0, d1, d2);
        res.y = trace_pair(cb, o0, o1, o2, d0, d1, d2);
        // Block writes one full contiguous 8-KB row this iteration; rows are
        // sequential across iterations -> one long stream per block.
        *(float2*)(outp + (size_t)i * N_SURF) = res;   // 8B-aligned dwordx2
    }
}

extern "C" void kernel_launch(void* const* d_in, const int* in_sizes, int n_in,
                              void* d_out, int out_size, void* d_ws, size_t ws_size,
                              hipStream_t stream) {
    const float* o  = (const float*)d_in[0];
    const float* dr = (const float*)d_in[1];
    const float* V  = (const float*)d_in[2];
    float* out = (float*)d_out;

    trace_kernel<<<dim3(N_RAYS / RPB), dim3(TPB), 0, stream>>>(o, dr, V, out);
}